// Round 1
// baseline (7638.653 us; speedup 1.0000x reference)
//
#include <hip/hip_runtime.h>
#include <cstdint>
#include <cstddef>

// Problem constants: B=64 (derived at launch), T=512, D=256, H=512
#define T_STEPS 512
#define D_DIM 256
#define H_DIM 512

// ---------------------------------------------------------------------------
// Kernel 1: xproj = inputs @ Wx + bias, written into d_out (same shape [B,T,H])
// Classic LDS-tiled fp32 GEMM. M=B*T, K=256, N=512. BM=64, BN=128, BK=32,
// 256 threads, 4x8 microtile per thread (split-N to keep LDS reads conflict-free).
// ---------------------------------------------------------------------------
#define BM 64
#define BN 128
#define BK 32

__global__ __launch_bounds__(256)
void xproj_gemm(const float* __restrict__ A, const float* __restrict__ Bm,
                const float* __restrict__ bias, float* __restrict__ C,
                int M, int N, int K) {
    __shared__ float As[BK][BM];   // transposed: As[k][m]
    __shared__ float Bs[BK][BN];   // Bs[k][n]

    const int tid = threadIdx.x;
    const int tx = tid & 15;       // 0..15 -> col groups
    const int ty = tid >> 4;       // 0..15 -> row groups
    const int row0 = blockIdx.y * BM;
    const int col0 = blockIdx.x * BN;

    float acc[4][8];
    #pragma unroll
    for (int i = 0; i < 4; ++i)
        #pragma unroll
        for (int j = 0; j < 8; ++j) acc[i][j] = 0.0f;

    for (int kt = 0; kt < K; kt += BK) {
        // A tile: 64 rows x 32 k = 512 float4; 2 per thread
        #pragma unroll
        for (int i = 0; i < 2; ++i) {
            int q  = tid + i * 256;       // 0..511
            int m  = q >> 3;              // q / (BK/4)
            int k4 = (q & 7) << 2;
            float4 v = *(const float4*)&A[(size_t)(row0 + m) * K + kt + k4];
            As[k4 + 0][m] = v.x; As[k4 + 1][m] = v.y;
            As[k4 + 2][m] = v.z; As[k4 + 3][m] = v.w;
        }
        // B tile: 32 k x 128 n = 1024 float4; 4 per thread
        #pragma unroll
        for (int i = 0; i < 4; ++i) {
            int q  = tid + i * 256;       // 0..1023
            int kk = q >> 5;              // q / (BN/4)
            int n4 = (q & 31) << 2;
            *(float4*)&Bs[kk][n4] = *(const float4*)&Bm[(size_t)(kt + kk) * N + col0 + n4];
        }
        __syncthreads();
        #pragma unroll
        for (int k = 0; k < BK; ++k) {
            float4 a  = *(const float4*)&As[k][ty << 2];
            float4 b0 = *(const float4*)&Bs[k][tx << 2];
            float4 b1 = *(const float4*)&Bs[k][(tx << 2) + 64];
            float av[4] = {a.x, a.y, a.z, a.w};
            float bv[8] = {b0.x, b0.y, b0.z, b0.w, b1.x, b1.y, b1.z, b1.w};
            #pragma unroll
            for (int i = 0; i < 4; ++i)
                #pragma unroll
                for (int j = 0; j < 8; ++j)
                    acc[i][j] = fmaf(av[i], bv[j], acc[i][j]);
        }
        __syncthreads();
    }

    // epilogue: + bias, store as 2 float4 per row
    float bv0[4], bv1[4];
    #pragma unroll
    for (int j = 0; j < 4; ++j) {
        bv0[j] = bias[col0 + (tx << 2) + j];
        bv1[j] = bias[col0 + (tx << 2) + 64 + j];
    }
    #pragma unroll
    for (int i = 0; i < 4; ++i) {
        int r = row0 + (ty << 2) + i;
        float4 o0 = make_float4(acc[i][0] + bv0[0], acc[i][1] + bv0[1],
                                acc[i][2] + bv0[2], acc[i][3] + bv0[3]);
        float4 o1 = make_float4(acc[i][4] + bv1[0], acc[i][5] + bv1[1],
                                acc[i][6] + bv1[2], acc[i][7] + bv1[3]);
        *(float4*)&C[(size_t)r * N + col0 + (tx << 2)]      = o0;
        *(float4*)&C[(size_t)r * N + col0 + (tx << 2) + 64] = o1;
    }
}

// ---------------------------------------------------------------------------
// Kernel 2: the sequential scan. One workgroup per batch row (zero inter-WG
// sync). 256 threads, each owns 2 adjacent columns (float2 Wh loads).
// h state in LDS. xproj is read from `out` and overwritten with h_t in place.
// ---------------------------------------------------------------------------
__device__ __forceinline__ float tanh_fast(float x) {
    float ax = fabsf(x);
    float e  = __expf(2.0f * ax);           // v_exp_f32 path
    float t  = 1.0f - 2.0f / (e + 1.0f);    // tanh(|x|), stable; e=inf -> 1
    return copysignf(t, x);
}

__global__ __launch_bounds__(256)
void rnn_scan(const float* __restrict__ Wh, const float* __restrict__ h0,
              const float* __restrict__ gamma, const float* __restrict__ beta,
              float* __restrict__ out) {
    const int b   = blockIdx.x;
    const int tid = threadIdx.x;          // 0..255
    const int c0  = tid * 2;
    const int c1  = c0 + 1;

    __shared__ float h_s[H_DIM];
    __shared__ float red_s[4], redq_s[4];

    h_s[c0] = h0[b * H_DIM + c0];
    h_s[c1] = h0[b * H_DIM + c1];
    const float g0  = gamma[c0], g1  = gamma[c1];
    const float be0 = beta[c0],  be1 = beta[c1];

    const float2* __restrict__ Wh2 = (const float2*)Wh;
    const float4* __restrict__ h4  = (const float4*)h_s;
    float* rowp = out + (size_t)b * T_STEPS * H_DIM;
    __syncthreads();

    #pragma unroll 1
    for (int t = 0; t < T_STEPS; ++t) {
        float acc0 = rowp[t * H_DIM + c0];
        float acc1 = rowp[t * H_DIM + c1];

        // z = xp + h @ Wh  (thread covers cols c0,c1; k-loop vectorized x4)
        #pragma unroll 4
        for (int k4 = 0; k4 < H_DIM / 4; ++k4) {
            float4 hv = h4[k4];
            float2 w0 = Wh2[(k4 * 4 + 0) * (H_DIM / 2) + tid];
            float2 w1 = Wh2[(k4 * 4 + 1) * (H_DIM / 2) + tid];
            float2 w2 = Wh2[(k4 * 4 + 2) * (H_DIM / 2) + tid];
            float2 w3 = Wh2[(k4 * 4 + 3) * (H_DIM / 2) + tid];
            acc0 = fmaf(hv.x, w0.x, acc0); acc1 = fmaf(hv.x, w0.y, acc1);
            acc0 = fmaf(hv.y, w1.x, acc0); acc1 = fmaf(hv.y, w1.y, acc1);
            acc0 = fmaf(hv.z, w2.x, acc0); acc1 = fmaf(hv.z, w2.y, acc1);
            acc0 = fmaf(hv.w, w3.x, acc0); acc1 = fmaf(hv.w, w3.y, acc1);
        }

        // LayerNorm stats over 512 cols: block reduce of sum and sumsq
        float s = acc0 + acc1;
        float q = acc0 * acc0 + acc1 * acc1;
        #pragma unroll
        for (int o = 32; o > 0; o >>= 1) {
            s += __shfl_down(s, o, 64);
            q += __shfl_down(q, o, 64);
        }
        const int wid  = tid >> 6;
        const int lane = tid & 63;
        if (lane == 0) { red_s[wid] = s; redq_s[wid] = q; }
        __syncthreads();   // also guarantees all k-loop reads of h_s are done
        float S = red_s[0] + red_s[1] + red_s[2] + red_s[3];
        float Q = redq_s[0] + redq_s[1] + redq_s[2] + redq_s[3];
        float mean = S * (1.0f / H_DIM);
        float var  = Q * (1.0f / H_DIM) - mean * mean;
        float rstd = rsqrtf(var + 1e-3f);   // keras LN eps

        float zn0 = (acc0 - mean) * rstd * g0 + be0;
        float zn1 = (acc1 - mean) * rstd * g1 + be1;
        float hn0 = tanh_fast(zn0);
        float hn1 = tanh_fast(zn1);

        rowp[t * H_DIM + c0] = hn0;       // overwrite xproj slot with output
        rowp[t * H_DIM + c1] = hn1;
        h_s[c0] = hn0;                    // safe: post-barrier, pre-next-read
        h_s[c1] = hn1;
        __syncthreads();
    }
}

// ---------------------------------------------------------------------------
extern "C" void kernel_launch(void* const* d_in, const int* in_sizes, int n_in,
                              void* d_out, int out_size, void* d_ws, size_t ws_size,
                              hipStream_t stream) {
    const float* inputs = (const float*)d_in[0];  // [B,T,D]
    const float* h0     = (const float*)d_in[1];  // [B,H]
    const float* Wx     = (const float*)d_in[2];  // [D,H]
    const float* Wh     = (const float*)d_in[3];  // [H,H]
    const float* bias   = (const float*)d_in[4];  // [H]
    const float* gamma  = (const float*)d_in[5];  // [H]
    const float* beta   = (const float*)d_in[6];  // [H]
    float* out = (float*)d_out;                   // [B,T,H]

    const int Bsz = in_sizes[0] / (T_STEPS * D_DIM);   // 64
    const int M = Bsz * T_STEPS;                        // 32768

    dim3 g1(H_DIM / BN, M / BM);   // (4, 512)
    xproj_gemm<<<g1, 256, 0, stream>>>(inputs, Wx, bias, out, M, H_DIM, D_DIM);

    rnn_scan<<<Bsz, 256, 0, stream>>>(Wh, h0, gamma, beta, out);
}

// Round 2
// 2873.431 us; speedup vs baseline: 2.6584x; 2.6584x over previous
//
#include <hip/hip_runtime.h>
#include <cstdint>
#include <cstddef>

// Problem constants: B=64, T=512, D=256, H=512
#define T_STEPS 512
#define D_DIM 256
#define H_DIM 512
#define B_SZ 64

// Scan decomposition: 4 column-groups of 128 cols per batch row.
// grid = 64 rows x 4 cg = 256 WGs of 512 threads; Wh slice (512x128 fp32 =
// 256 KB) lives entirely in registers (128 VGPR/thread), loaded once.
#define NCG 4
#define CGW (H_DIM / NCG)   // 128
#define NTH 512

// d_ws layout:
//   [0, 128K)        ctr  : int  [64 rows][512 steps]   (memset 0 each call)
//   [128K, 384K)     zbuf : float[64 rows][2 parity][512]
#define WS_CTR_BYTES (B_SZ * T_STEPS * 4)

// ---------------------------------------------------------------------------
// Kernel 1: xproj = inputs @ Wx + bias  ->  d_out  [B*T, H]
// ---------------------------------------------------------------------------
#define BM 64
#define BN 128
#define BK 32

__global__ __launch_bounds__(256)
void xproj_gemm(const float* __restrict__ A, const float* __restrict__ Bm,
                const float* __restrict__ bias, float* __restrict__ C,
                int M, int N, int K) {
    __shared__ float As[BK][BM];
    __shared__ float Bs[BK][BN];

    const int tid = threadIdx.x;
    const int tx = tid & 15;
    const int ty = tid >> 4;
    const int row0 = blockIdx.y * BM;
    const int col0 = blockIdx.x * BN;

    float acc[4][8];
    #pragma unroll
    for (int i = 0; i < 4; ++i)
        #pragma unroll
        for (int j = 0; j < 8; ++j) acc[i][j] = 0.0f;

    for (int kt = 0; kt < K; kt += BK) {
        #pragma unroll
        for (int i = 0; i < 2; ++i) {
            int q  = tid + i * 256;
            int m  = q >> 3;
            int k4 = (q & 7) << 2;
            float4 v = *(const float4*)&A[(size_t)(row0 + m) * K + kt + k4];
            As[k4 + 0][m] = v.x; As[k4 + 1][m] = v.y;
            As[k4 + 2][m] = v.z; As[k4 + 3][m] = v.w;
        }
        #pragma unroll
        for (int i = 0; i < 4; ++i) {
            int q  = tid + i * 256;
            int kk = q >> 5;
            int n4 = (q & 31) << 2;
            *(float4*)&Bs[kk][n4] = *(const float4*)&Bm[(size_t)(kt + kk) * N + col0 + n4];
        }
        __syncthreads();
        #pragma unroll
        for (int k = 0; k < BK; ++k) {
            float4 a  = *(const float4*)&As[k][ty << 2];
            float4 b0 = *(const float4*)&Bs[k][tx << 2];
            float4 b1 = *(const float4*)&Bs[k][(tx << 2) + 64];
            float av[4] = {a.x, a.y, a.z, a.w};
            float bv[8] = {b0.x, b0.y, b0.z, b0.w, b1.x, b1.y, b1.z, b1.w};
            #pragma unroll
            for (int i = 0; i < 4; ++i)
                #pragma unroll
                for (int j = 0; j < 8; ++j)
                    acc[i][j] = fmaf(av[i], bv[j], acc[i][j]);
        }
        __syncthreads();
    }

    float bv0[4], bv1[4];
    #pragma unroll
    for (int j = 0; j < 4; ++j) {
        bv0[j] = bias[col0 + (tx << 2) + j];
        bv1[j] = bias[col0 + (tx << 2) + 64 + j];
    }
    #pragma unroll
    for (int i = 0; i < 4; ++i) {
        int r = row0 + (ty << 2) + i;
        float4 o0 = make_float4(acc[i][0] + bv0[0], acc[i][1] + bv0[1],
                                acc[i][2] + bv0[2], acc[i][3] + bv0[3]);
        float4 o1 = make_float4(acc[i][4] + bv1[0], acc[i][5] + bv1[1],
                                acc[i][6] + bv1[2], acc[i][7] + bv1[3]);
        *(float4*)&C[(size_t)r * N + col0 + (tx << 2)]      = o0;
        *(float4*)&C[(size_t)r * N + col0 + (tx << 2) + 64] = o1;
    }
}

// ---------------------------------------------------------------------------
// Kernel 2: the scan. 256 WGs = 64 rows x 4 col-groups. Per-step cross-WG
// exchange of the z row via device-coherent buffer + per-step arrival counter.
// ---------------------------------------------------------------------------
__device__ __forceinline__ float tanh_fast(float x) {
    float ax = fabsf(x);
    float e  = __expf(2.0f * ax);
    float t  = 1.0f - 2.0f / (e + 1.0f);
    return copysignf(t, x);
}

__global__ __launch_bounds__(NTH)
void rnn_scan2(const float* __restrict__ Wh, const float* __restrict__ h0,
               const float* __restrict__ gamma, const float* __restrict__ beta,
               float* __restrict__ out,
               int* __restrict__ ctr, float* __restrict__ zbuf) {
    const int r   = blockIdx.x & (B_SZ - 1);   // row: quartet members share r
    const int cg  = blockIdx.x >> 6;           // 0..3 (stride 64 -> same XCD)
    const int tid = threadIdx.x;               // 0..511
    const int c   = tid & (CGW - 1);           // 0..127
    const int kc  = tid >> 7;                  // 0..3  (wave-uniform)
    const int cglob = cg * CGW + c;

    __shared__ float h_s[H_DIM];
    __shared__ float part_s[NCG][CGW];
    __shared__ float wred_s[16];
    __shared__ float stat_s[2];

    // Load Wh register slice: w[j] = Wh[kc*128 + j][cglob]  (coalesced per j)
    float w[128];
    #pragma unroll
    for (int j = 0; j < 128; ++j)
        w[j] = Wh[(size_t)(kc * 128 + j) * H_DIM + cglob];

    h_s[tid] = h0[r * H_DIM + tid];            // NTH == H_DIM
    const float g_own = gamma[tid];
    const float b_own = beta[tid];
    float* outrow = out + (size_t)r * T_STEPS * H_DIM;
    __syncthreads();

    for (int t = 0; t < T_STEPS; ++t) {
        // xp for own slice (independent load, overlaps the GEMM below)
        float xp = 0.0f;
        if (tid < CGW) xp = outrow[t * H_DIM + cg * CGW + tid];

        // partial z: acc = sum_j w[j] * h[kc*128 + j]   (h reads broadcast)
        float acc = 0.0f;
        const float4* h4 = (const float4*)&h_s[kc * 128];
        #pragma unroll
        for (int j4 = 0; j4 < 32; ++j4) {
            float4 hv = h4[j4];
            acc = fmaf(w[4 * j4 + 0], hv.x, acc);
            acc = fmaf(w[4 * j4 + 1], hv.y, acc);
            acc = fmaf(w[4 * j4 + 2], hv.z, acc);
            acc = fmaf(w[4 * j4 + 3], hv.w, acc);
        }
        part_s[kc][c] = acc;
        __syncthreads();

        const int p = t & 1;
        float* zb = zbuf + (size_t)(r * 2 + p) * H_DIM;
        if (tid < CGW) {
            float z = xp + part_s[0][tid] + part_s[1][tid]
                         + part_s[2][tid] + part_s[3][tid];
            __hip_atomic_store(&zb[cg * CGW + tid], z,
                               __ATOMIC_RELAXED, __HIP_MEMORY_SCOPE_AGENT);
        }
        __syncthreads();   // drains the coherent stores (vmcnt) before signal

        if (tid == 0) {
            int* cp = &ctr[r * T_STEPS + t];
            __hip_atomic_fetch_add(cp, 1, __ATOMIC_RELEASE,
                                   __HIP_MEMORY_SCOPE_AGENT);
            while (__hip_atomic_load(cp, __ATOMIC_ACQUIRE,
                                     __HIP_MEMORY_SCOPE_AGENT) < NCG) {}
        }
        __syncthreads();

        // full z row now published; this thread owns column `tid`
        float z = __hip_atomic_load(&zb[tid], __ATOMIC_RELAXED,
                                    __HIP_MEMORY_SCOPE_AGENT);

        // LN stats over 512 (wave shuffle + tiny LDS combine)
        float s = z, q = z * z;
        #pragma unroll
        for (int o = 32; o > 0; o >>= 1) {
            s += __shfl_down(s, o, 64);
            q += __shfl_down(q, o, 64);
        }
        const int wid = tid >> 6, lane = tid & 63;
        if (lane == 0) { wred_s[wid] = s; wred_s[8 + wid] = q; }
        __syncthreads();
        if (tid == 0) {
            float S = 0.0f, Q = 0.0f;
            #pragma unroll
            for (int i = 0; i < 8; ++i) { S += wred_s[i]; Q += wred_s[8 + i]; }
            float mean = S * (1.0f / H_DIM);
            float var  = Q * (1.0f / H_DIM) - mean * mean;
            stat_s[0] = mean;
            stat_s[1] = rsqrtf(var + 1e-3f);
        }
        __syncthreads();
        float mean = stat_s[0], rstd = stat_s[1];
        float hn = tanh_fast((z - mean) * rstd * g_own + b_own);
        h_s[tid] = hn;                              // full row kept locally
        if ((tid >> 7) == cg) outrow[t * H_DIM + tid] = hn;  // own slice only
        __syncthreads();
    }
}

// ---------------------------------------------------------------------------
extern "C" void kernel_launch(void* const* d_in, const int* in_sizes, int n_in,
                              void* d_out, int out_size, void* d_ws, size_t ws_size,
                              hipStream_t stream) {
    const float* inputs = (const float*)d_in[0];  // [B,T,D]
    const float* h0     = (const float*)d_in[1];  // [B,H]
    const float* Wx     = (const float*)d_in[2];  // [D,H]
    const float* Wh     = (const float*)d_in[3];  // [H,H]
    const float* bias   = (const float*)d_in[4];  // [H]
    const float* gamma  = (const float*)d_in[5];  // [H]
    const float* beta   = (const float*)d_in[6];  // [H]
    float* out = (float*)d_out;                   // [B,T,H]

    int*   ctr  = (int*)d_ws;
    float* zbuf = (float*)((char*)d_ws + WS_CTR_BYTES);

    // arrival counters must start at 0 every call (ws is poisoned 0xAA)
    hipMemsetAsync(d_ws, 0, WS_CTR_BYTES, stream);

    const int M = B_SZ * T_STEPS;                 // 32768
    dim3 g1(H_DIM / BN, M / BM);                  // (4, 512)
    xproj_gemm<<<g1, 256, 0, stream>>>(inputs, Wx, bias, out, M, H_DIM, D_DIM);

    rnn_scan2<<<B_SZ * NCG, NTH, 0, stream>>>(Wh, h0, gamma, beta, out,
                                              ctr, zbuf);
}

// Round 3
// 1242.769 us; speedup vs baseline: 6.1465x; 2.3121x over previous
//
#include <hip/hip_runtime.h>
#include <cstdint>
#include <cstddef>

// Problem constants: B=64, T=512, D=256, H=512
#define T_STEPS 512
#define D_DIM 256
#define H_DIM 512
#define B_SZ 64

// Scan decomposition: 4 column-groups of 128 cols per batch row.
// grid = 64 rows x 4 cg = 256 WGs of 512 threads; Wh slice (512x128 fp32 =
// 256 KB) lives entirely in registers (128 VGPR/thread), loaded once.
// Cross-WG exchange: single-hop (tag,z) 8-byte packets at AGENT scope.
#define NCG 4
#define CGW (H_DIM / NCG)   // 128
#define NTH 512

// d_ws layout: zbuf : uint64 [64 rows][2 parity][512 cols]  = 512 KB
// No memset needed: 0xAAAAAAAA poison never equals a tag in 1..512.

// ---------------------------------------------------------------------------
// Kernel 1: xproj = inputs @ Wx + bias  ->  d_out  [B*T, H]
// ---------------------------------------------------------------------------
#define BM 64
#define BN 128
#define BK 32

__global__ __launch_bounds__(256)
void xproj_gemm(const float* __restrict__ A, const float* __restrict__ Bm,
                const float* __restrict__ bias, float* __restrict__ C,
                int M, int N, int K) {
    __shared__ float As[BK][BM];
    __shared__ float Bs[BK][BN];

    const int tid = threadIdx.x;
    const int tx = tid & 15;
    const int ty = tid >> 4;
    const int row0 = blockIdx.y * BM;
    const int col0 = blockIdx.x * BN;

    float acc[4][8];
    #pragma unroll
    for (int i = 0; i < 4; ++i)
        #pragma unroll
        for (int j = 0; j < 8; ++j) acc[i][j] = 0.0f;

    for (int kt = 0; kt < K; kt += BK) {
        #pragma unroll
        for (int i = 0; i < 2; ++i) {
            int q  = tid + i * 256;
            int m  = q >> 3;
            int k4 = (q & 7) << 2;
            float4 v = *(const float4*)&A[(size_t)(row0 + m) * K + kt + k4];
            As[k4 + 0][m] = v.x; As[k4 + 1][m] = v.y;
            As[k4 + 2][m] = v.z; As[k4 + 3][m] = v.w;
        }
        #pragma unroll
        for (int i = 0; i < 4; ++i) {
            int q  = tid + i * 256;
            int kk = q >> 5;
            int n4 = (q & 31) << 2;
            *(float4*)&Bs[kk][n4] = *(const float4*)&Bm[(size_t)(kt + kk) * N + col0 + n4];
        }
        __syncthreads();
        #pragma unroll
        for (int k = 0; k < BK; ++k) {
            float4 a  = *(const float4*)&As[k][ty << 2];
            float4 b0 = *(const float4*)&Bs[k][tx << 2];
            float4 b1 = *(const float4*)&Bs[k][(tx << 2) + 64];
            float av[4] = {a.x, a.y, a.z, a.w};
            float bv[8] = {b0.x, b0.y, b0.z, b0.w, b1.x, b1.y, b1.z, b1.w};
            #pragma unroll
            for (int i = 0; i < 4; ++i)
                #pragma unroll
                for (int j = 0; j < 8; ++j)
                    acc[i][j] = fmaf(av[i], bv[j], acc[i][j]);
        }
        __syncthreads();
    }

    float bv0[4], bv1[4];
    #pragma unroll
    for (int j = 0; j < 4; ++j) {
        bv0[j] = bias[col0 + (tx << 2) + j];
        bv1[j] = bias[col0 + (tx << 2) + 64 + j];
    }
    #pragma unroll
    for (int i = 0; i < 4; ++i) {
        int r = row0 + (ty << 2) + i;
        float4 o0 = make_float4(acc[i][0] + bv0[0], acc[i][1] + bv0[1],
                                acc[i][2] + bv0[2], acc[i][3] + bv0[3]);
        float4 o1 = make_float4(acc[i][4] + bv1[0], acc[i][5] + bv1[1],
                                acc[i][6] + bv1[2], acc[i][7] + bv1[3]);
        *(float4*)&C[(size_t)r * N + col0 + (tx << 2)]      = o0;
        *(float4*)&C[(size_t)r * N + col0 + (tx << 2) + 64] = o1;
    }
}

// ---------------------------------------------------------------------------
// Kernel 2: the scan. 256 WGs = 64 rows x 4 col-groups. Single-hop exchange:
// producers publish (tag|z) packets; every thread polls the packet for the
// column it needs. Thread tid handles GEMM k-chunk kc=tid>>7 for column
// c=tid&127 of its own slice, and polls/owns global column `tid` for LN/h.
// ---------------------------------------------------------------------------
__device__ __forceinline__ float tanh_fast(float x) {
    float ax = fabsf(x);
    float e  = __expf(2.0f * ax);
    float t  = 1.0f - 2.0f / (e + 1.0f);
    return copysignf(t, x);
}

__global__ __launch_bounds__(NTH)
void rnn_scan3(const float* __restrict__ Wh, const float* __restrict__ h0,
               const float* __restrict__ gamma, const float* __restrict__ beta,
               float* __restrict__ out,
               unsigned long long* __restrict__ zbuf) {
    const int r   = blockIdx.x & (B_SZ - 1);   // row; quartet shares r
    const int cg  = blockIdx.x >> 6;           // 0..3 (stride 64 -> same XCD)
    const int tid = threadIdx.x;               // 0..511
    const int c   = tid & (CGW - 1);           // 0..127
    const int kc  = tid >> 7;                  // 0..3 (wave-uniform)

    __shared__ float h_s[H_DIM];
    __shared__ float part_s[NCG][CGW];
    __shared__ float wred_s[16];

    // Wh register slice: w[j] = Wh[kc*128 + j][cg*128 + c]
    float w[128];
    #pragma unroll
    for (int j = 0; j < 128; ++j)
        w[j] = Wh[(size_t)(kc * 128 + j) * H_DIM + cg * CGW + c];

    h_s[tid] = h0[r * H_DIM + tid];            // NTH == H_DIM
    const float g_own = gamma[tid];
    const float b_own = beta[tid];
    float* outrow = out + (size_t)r * T_STEPS * H_DIM;
    unsigned long long* zrow0 = zbuf + (size_t)(r * 2) * H_DIM;
    __syncthreads();

    for (int t = 0; t < T_STEPS; ++t) {
        unsigned long long* zrow = zrow0 + (size_t)(t & 1) * H_DIM;
        const unsigned int tag = (unsigned int)(t + 1);

        // xp for producer threads (covers own slice), overlaps the GEMM
        float xp = 0.0f;
        if (tid < CGW) xp = outrow[t * H_DIM + cg * CGW + tid];

        // partial z for own slice: acc = sum_j w[j] * h[kc*128 + j]
        float acc = 0.0f;
        const float4* h4 = (const float4*)&h_s[kc * 128];
        #pragma unroll
        for (int j4 = 0; j4 < 32; ++j4) {
            float4 hv = h4[j4];
            acc = fmaf(w[4 * j4 + 0], hv.x, acc);
            acc = fmaf(w[4 * j4 + 1], hv.y, acc);
            acc = fmaf(w[4 * j4 + 2], hv.z, acc);
            acc = fmaf(w[4 * j4 + 3], hv.w, acc);
        }
        part_s[kc][c] = acc;
        __syncthreads();                                   // barrier A

        // producers: combine partials, publish (tag|z) packet — single hop
        if (tid < CGW) {
            float z = xp + part_s[0][tid] + part_s[1][tid]
                         + part_s[2][tid] + part_s[3][tid];
            unsigned long long pkt =
                ((unsigned long long)tag << 32) | (unsigned long long)__float_as_uint(z);
            __hip_atomic_store(&zrow[cg * CGW + tid], pkt,
                               __ATOMIC_RELAXED, __HIP_MEMORY_SCOPE_AGENT);
        }

        // every thread polls the packet for global column `tid`
        unsigned long long pkt;
        do {
            pkt = __hip_atomic_load(&zrow[tid], __ATOMIC_RELAXED,
                                    __HIP_MEMORY_SCOPE_AGENT);
        } while ((unsigned int)(pkt >> 32) != tag);
        float z = __uint_as_float((unsigned int)pkt);

        // LN stats over 512: wave shuffle + LDS, combined redundantly by all
        float s = z, q = z * z;
        #pragma unroll
        for (int o = 32; o > 0; o >>= 1) {
            s += __shfl_down(s, o, 64);
            q += __shfl_down(q, o, 64);
        }
        const int wid = tid >> 6;
        if ((tid & 63) == 0) { wred_s[wid] = s; wred_s[8 + wid] = q; }
        __syncthreads();                                   // barrier B
        float S = 0.0f, Q = 0.0f;
        #pragma unroll
        for (int i = 0; i < 8; ++i) { S += wred_s[i]; Q += wred_s[8 + i]; }
        float mean = S * (1.0f / H_DIM);
        float var  = Q * (1.0f / H_DIM) - mean * mean;
        float rstd = rsqrtf(var + 1e-3f);                  // keras LN eps

        float hn = tanh_fast((z - mean) * rstd * g_own + b_own);
        if (kc == cg) outrow[t * H_DIM + tid] = hn;        // own slice store
        h_s[tid] = hn;            // safe: all h_s reads ended before barrier A
        __syncthreads();                                   // barrier C
    }
}

// ---------------------------------------------------------------------------
extern "C" void kernel_launch(void* const* d_in, const int* in_sizes, int n_in,
                              void* d_out, int out_size, void* d_ws, size_t ws_size,
                              hipStream_t stream) {
    const float* inputs = (const float*)d_in[0];  // [B,T,D]
    const float* h0     = (const float*)d_in[1];  // [B,H]
    const float* Wx     = (const float*)d_in[2];  // [D,H]
    const float* Wh     = (const float*)d_in[3];  // [H,H]
    const float* bias   = (const float*)d_in[4];  // [H]
    const float* gamma  = (const float*)d_in[5];  // [H]
    const float* beta   = (const float*)d_in[6];  // [H]
    float* out = (float*)d_out;                   // [B,T,H]

    unsigned long long* zbuf = (unsigned long long*)d_ws;  // 512 KB

    const int M = B_SZ * T_STEPS;                 // 32768
    dim3 g1(H_DIM / BN, M / BM);                  // (4, 512)
    xproj_gemm<<<g1, 256, 0, stream>>>(inputs, Wx, bias, out, M, H_DIM, D_DIM);

    rnn_scan3<<<B_SZ * NCG, NTH, 0, stream>>>(Wh, h0, gamma, beta, out, zbuf);
}